// Round 8
// baseline (156.370 us; speedup 1.0000x reference)
//
#include <hip/hip_runtime.h>
#include <math.h>

#define N_NODES 8192
#define FDIM 256
#define DDIM 128
#define SLOPE 0.2f
#define ELLW 128   // max kept neighbors/row; true max deg ~56 for Binom(262144, 1/8192)
#define GR 32      // gemm rows per block
#define GRID 512   // exactly 2 blocks/CU on 256 CUs — co-resident by construction

// ---------------- tiny: zero the grid-barrier counter (fresh each launch) -----------
__global__ void zero_ctr(unsigned* __restrict__ c) {
    if (threadIdx.x < 2) c[threadIdx.x] = 0u;
}

// ---------------- software grid barrier (device-scope, XCD-safe) --------------------
__device__ __forceinline__ void grid_barrier(unsigned* ctr, unsigned target) {
    __syncthreads();
    if (threadIdx.x == 0) {
        __threadfence();                          // release: my global writes visible device-wide
        atomicAdd(ctr, 1u);
        while (atomicAdd(ctr, 0u) < target) {}    // coherent device-scope poll
        __threadfence();                          // acquire
    }
    __syncthreads();
}

// ---------------- fused: {cnt-zero + GEMM} | barrier | ELL | barrier | rows ---------
__global__ __launch_bounds__(256, 2) void glcn_fused(const int* __restrict__ edge, int E,
                                                     const float* __restrict__ X,
                                                     const float* __restrict__ Ws,
                                                     const float* __restrict__ a,
                                                     float* __restrict__ Wh,
                                                     float* __restrict__ s1p,
                                                     float* __restrict__ s2p,
                                                     unsigned* __restrict__ cnt,
                                                     unsigned* __restrict__ ell,
                                                     float* __restrict__ out,
                                                     unsigned* __restrict__ gctr) {
    __shared__ float4 smem4[GR * 65 + 64 * 16];   // 49,664 B; gemm tiles / row-phase alias
    float4* xs4 = smem4;                          // 32 rows x 64 float4, stride 65 (bank-pad)
    float4* ws4 = smem4 + GR * 65;                // 64 k x 16 float4 (64 cols)
    int t = threadIdx.x;

    // ---- P0: zero ELL counters (before barrier 1; build_ell is after) ----
    if (t < 16) cnt[blockIdx.x * 16 + t] = 0u;

    // ---- P1: GEMM Wh = X @ Ws, 32x64 tile, fused partial s1/s2 ----
    {
        int rb = blockIdx.x >> 1, cb = blockIdx.x & 1;
        int row0 = rb * GR;
        const float4* Xg = (const float4*)(X + (size_t)row0 * FDIM);
        for (int i = t; i < GR * 64; i += 256) {
            int r = i >> 6, j = i & 63;
            xs4[r * 65 + j] = Xg[i];
        }
        int rg = t >> 4, cg = t & 15;
        float4 acc0 = make_float4(0.f, 0.f, 0.f, 0.f);
        float4 acc1 = make_float4(0.f, 0.f, 0.f, 0.f);

        for (int c = 0; c < 4; c++) {
            __syncthreads();          // prev chunk consumed (covers xs4 at c=0)
            const float* Wsrc = Ws + (size_t)(c * 64) * DDIM + cb * 64;
            for (int i = t; i < 1024; i += 256) {
                int kk = i >> 4, cc = i & 15;
                ws4[i] = ((const float4*)(Wsrc + (size_t)kk * DDIM))[cc];
            }
            __syncthreads();          // chunk staged
#pragma unroll 4
            for (int kk = 0; kk < 64; kk += 4) {
                float4 w0 = ws4[(kk + 0) * 16 + cg];
                float4 w1 = ws4[(kk + 1) * 16 + cg];
                float4 w2 = ws4[(kk + 2) * 16 + cg];
                float4 w3 = ws4[(kk + 3) * 16 + cg];
                float4 x0 = xs4[(rg * 2 + 0) * 65 + c * 16 + (kk >> 2)];
                float4 x1 = xs4[(rg * 2 + 1) * 65 + c * 16 + (kk >> 2)];
                // pure-FMA form: 32 fmaf, 16 independent chains
                acc0.x = fmaf(x0.x, w0.x, acc0.x); acc0.x = fmaf(x0.y, w1.x, acc0.x);
                acc0.x = fmaf(x0.z, w2.x, acc0.x); acc0.x = fmaf(x0.w, w3.x, acc0.x);
                acc0.y = fmaf(x0.x, w0.y, acc0.y); acc0.y = fmaf(x0.y, w1.y, acc0.y);
                acc0.y = fmaf(x0.z, w2.y, acc0.y); acc0.y = fmaf(x0.w, w3.y, acc0.y);
                acc0.z = fmaf(x0.x, w0.z, acc0.z); acc0.z = fmaf(x0.y, w1.z, acc0.z);
                acc0.z = fmaf(x0.z, w2.z, acc0.z); acc0.z = fmaf(x0.w, w3.z, acc0.z);
                acc0.w = fmaf(x0.x, w0.w, acc0.w); acc0.w = fmaf(x0.y, w1.w, acc0.w);
                acc0.w = fmaf(x0.z, w2.w, acc0.w); acc0.w = fmaf(x0.w, w3.w, acc0.w);
                acc1.x = fmaf(x1.x, w0.x, acc1.x); acc1.x = fmaf(x1.y, w1.x, acc1.x);
                acc1.x = fmaf(x1.z, w2.x, acc1.x); acc1.x = fmaf(x1.w, w3.x, acc1.x);
                acc1.y = fmaf(x1.x, w0.y, acc1.y); acc1.y = fmaf(x1.y, w1.y, acc1.y);
                acc1.y = fmaf(x1.z, w2.y, acc1.y); acc1.y = fmaf(x1.w, w3.y, acc1.y);
                acc1.z = fmaf(x1.x, w0.z, acc1.z); acc1.z = fmaf(x1.y, w1.z, acc1.z);
                acc1.z = fmaf(x1.z, w2.z, acc1.z); acc1.z = fmaf(x1.w, w3.z, acc1.z);
                acc1.w = fmaf(x1.x, w0.w, acc1.w); acc1.w = fmaf(x1.y, w1.w, acc1.w);
                acc1.w = fmaf(x1.z, w2.w, acc1.w); acc1.w = fmaf(x1.w, w3.w, acc1.w);
            }
        }

        ((float4*)(Wh + (size_t)(row0 + rg * 2 + 0) * DDIM))[cb * 16 + cg] = acc0;
        ((float4*)(Wh + (size_t)(row0 + rg * 2 + 1) * DDIM))[cb * 16 + cg] = acc1;

        float4 a1 = ((const float4*)a)[cb * 16 + cg];
        float4 a2 = ((const float4*)a)[32 + cb * 16 + cg];
        float p10 = acc0.x * a1.x + acc0.y * a1.y + acc0.z * a1.z + acc0.w * a1.w;
        float p20 = acc0.x * a2.x + acc0.y * a2.y + acc0.z * a2.z + acc0.w * a2.w;
        float p11 = acc1.x * a1.x + acc1.y * a1.y + acc1.z * a1.z + acc1.w * a1.w;
        float p21 = acc1.x * a2.x + acc1.y * a2.y + acc1.z * a2.z + acc1.w * a2.w;
        for (int o = 8; o; o >>= 1) {
            p10 += __shfl_xor(p10, o, 16);
            p20 += __shfl_xor(p20, o, 16);
            p11 += __shfl_xor(p11, o, 16);
            p21 += __shfl_xor(p21, o, 16);
        }
        if (cg == 0) {
            size_t base = (size_t)cb * N_NODES;
            s1p[base + row0 + rg * 2 + 0] = p10;
            s2p[base + row0 + rg * 2 + 0] = p20;
            s1p[base + row0 + rg * 2 + 1] = p11;
            s2p[base + row0 + rg * 2 + 1] = p21;
        }
    }

    grid_barrier(gctr, GRID);         // cnt zeroed + (Wh, s1p, s2p) visible

    // ---- P2: ELL build (grid-stride, coalesced) ----
    for (int e = blockIdx.x * 256 + t; e < E; e += GRID * 256) {
        int r = edge[e];
        int c = edge[E + e];
        unsigned slot = atomicAdd(&cnt[r], 1u);
        if (slot < ELLW) ell[(size_t)r * ELLW + slot] = (unsigned)c;
    }

    grid_barrier(gctr, 2 * GRID);     // cnt/ell visible

    // ---- P3: rows — wave-per-row, 4 rows per wave ----
    {
        unsigned* bmw = (unsigned*)smem4;                 // [4][256] dedup bitmaps (4KB)
        float*    plv = (float*)(bmw + 4 * 256);          // [4][128]
        unsigned* jlv = (unsigned*)(plv + 4 * 128);       // [4][128]
        int w = t >> 6, lane = t & 63;
        const float2* Wh2 = (const float2*)Wh;

        for (int it = 0; it < 4; ++it) {
            ((uint4*)(bmw + w * 256))[lane] = make_uint4(0u, 0u, 0u, 0u);
            __syncthreads();          // uniform: all waves, every iteration
            int i = blockIdx.x * 16 + w * 4 + it;
            unsigned deg = cnt[i];
            if (deg > ELLW) deg = ELLW;

            if (deg == 0u) {
                // all-masked row -> uniform softmax -> elu(mean(Wh)); never taken here
                float sx = 0.f, sy = 0.f;
                for (int rr = 0; rr < N_NODES; rr++) {
                    float2 v = Wh2[(size_t)rr * 64 + lane];
                    sx += v.x; sy += v.y;
                }
                sx *= (1.0f / N_NODES); sy *= (1.0f / N_NODES);
                sx = sx > 0.f ? sx : __expf(sx) - 1.f;
                sy = sy > 0.f ? sy : __expf(sy) - 1.f;
                ((float2*)out)[(size_t)i * 64 + lane] = make_float2(sx, sy);
                continue;             // next iteration's __syncthreads is still reached by all
            }

            const unsigned* erow = ell + (size_t)i * ELLW;
            unsigned j0 = 0u, j1 = 0u;
            bool v0 = false, v1 = false;
            if (lane < (int)deg) j0 = erow[lane];
            if (lane + 64 < (int)deg) j1 = erow[lane + 64];
            if (lane < (int)deg) {
                unsigned m = 1u << (j0 & 31);
                v0 = !(atomicOr(&bmw[w * 256 + (j0 >> 5)], m) & m);
            }
            if (lane + 64 < (int)deg) {
                unsigned m = 1u << (j1 & 31);
                v1 = !(atomicOr(&bmw[w * 256 + (j1 >> 5)], m) & m);
            }

            float s1 = s1p[i] + s1p[N_NODES + i];
            float e0 = -3e38f, e1 = -3e38f;
            if (v0) { float e = s1 + s2p[j0] + s2p[N_NODES + j0]; e0 = e > 0.f ? e : SLOPE * e; }
            if (v1) { float e = s1 + s2p[j1] + s2p[N_NODES + j1]; e1 = e > 0.f ? e : SLOPE * e; }

            float mx = fmaxf(e0, e1);
            for (int o = 32; o; o >>= 1) mx = fmaxf(mx, __shfl_xor(mx, o, 64));

            float p0 = v0 ? __expf(e0 - mx) : 0.f;
            float p1 = v1 ? __expf(e1 - mx) : 0.f;
            float s = p0 + p1;
            for (int o = 32; o; o >>= 1) s += __shfl_xor(s, o, 64);
            float inv = 1.0f / s;

            plv[w * ELLW + lane] = p0;      jlv[w * ELLW + lane] = j0;
            plv[w * ELLW + lane + 64] = p1; jlv[w * ELLW + lane + 64] = j1;

            float ax = 0.f, ay = 0.f;
#pragma unroll 4
            for (unsigned n = 0; n < deg; ++n) {
                float p = plv[w * ELLW + n];     // LDS broadcast
                unsigned j = jlv[w * ELLW + n];
                float2 v = Wh2[(size_t)j * 64 + lane];
                ax = fmaf(p, v.x, ax); ay = fmaf(p, v.y, ay);
            }
            ax *= inv; ay *= inv;
            ax = ax > 0.f ? ax : __expf(ax) - 1.f;
            ay = ay > 0.f ? ay : __expf(ay) - 1.f;
            ((float2*)out)[(size_t)i * 64 + lane] = make_float2(ax, ay);
        }
    }
}

extern "C" void kernel_launch(void* const* d_in, const int* in_sizes, int n_in,
                              void* d_out, int out_size, void* d_ws, size_t ws_size,
                              hipStream_t stream) {
    const int*   edge = (const int*)d_in[0];    // [2, E] int32
    const float* X    = (const float*)d_in[1];  // [N, F]
    const float* Ws   = (const float*)d_in[2];  // [F, D]
    const float* a    = (const float*)d_in[3];  // [2D, 1]
    float*       out  = (float*)d_out;          // [N, D]
    int E = in_sizes[0] / 2;

    char* ws = (char*)d_ws;
    unsigned* cnt  = (unsigned*)ws;                                        // 32 KB
    unsigned* gctr = cnt + N_NODES;                                        // 8 B
    unsigned* ell  = (unsigned*)(ws + 64 * 1024);                          // 4 MB
    float*    s1p  = (float*)(ws + 64 * 1024 + (size_t)N_NODES * ELLW * 4);// 2 x 32 KB
    float*    s2p  = s1p + 2 * N_NODES;                                    // 2 x 32 KB
    float*    Wh   = s2p + 2 * N_NODES;                                    // 4 MB

    zero_ctr<<<1, 64, 0, stream>>>(gctr);
    glcn_fused<<<GRID, 256, 0, stream>>>(edge, E, X, Ws, a, Wh, s1p, s2p,
                                         cnt, ell, out, gctr);
}

// Round 9
// 116.101 us; speedup vs baseline: 1.3468x; 1.3468x over previous
//
#include <hip/hip_runtime.h>
#include <math.h>

#define N_NODES 8192
#define FDIM 256
#define DDIM 128
#define SLOPE 0.2f
#define ELLW 128   // max kept slots/row (incl. dups); true max ~56, validated R5-R8
#define GR 32      // gemm rows per block
#define GRID 512   // 2 blocks/CU x 256 CUs — co-resident by construction (validated R8)

// ---------------- k0: zero cnt + s1 + s2 + barrier counter --------------------------
__global__ __launch_bounds__(256) void zero_k(unsigned* __restrict__ cnt,
                                              float* __restrict__ s1,
                                              float* __restrict__ s2,
                                              unsigned* __restrict__ gctr) {
    int i = blockIdx.x * 256 + threadIdx.x;   // grid = 32 blocks -> i in [0,8192)
    cnt[i] = 0u;
    s1[i] = 0.f;
    s2[i] = 0.f;
    if (i == 0) gctr[0] = 0u;
}

// ---------------- grid barrier: RMW arrive, LOAD spin (R8's RMW-spin cost ~110us) ---
__device__ __forceinline__ void grid_barrier(unsigned* ctr) {
    __syncthreads();
    if (threadIdx.x == 0) {
        __threadfence();                      // release: my global stores visible device-wide
        atomicAdd(ctr, 1u);                   // one RMW per block
        while (__hip_atomic_load(ctr, __ATOMIC_RELAXED, __HIP_MEMORY_SCOPE_AGENT) < GRID) {
            __builtin_amdgcn_s_sleep(4);      // ~107ns nap: keep poll traffic tiny
        }
        __threadfence();                      // acquire
    }
    __syncthreads();
}

// ---------------- fused: {GEMM ; ELL} | barrier | rows ------------------------------
__global__ __launch_bounds__(256, 2) void glcn_fused(const int* __restrict__ edge, int E,
                                                     const float* __restrict__ X,
                                                     const float* __restrict__ Ws,
                                                     const float* __restrict__ a,
                                                     float* __restrict__ Wh,
                                                     float* __restrict__ s1,
                                                     float* __restrict__ s2,
                                                     unsigned* __restrict__ cnt,
                                                     unsigned* __restrict__ ell,
                                                     float* __restrict__ out,
                                                     unsigned* __restrict__ gctr) {
    __shared__ float4 smem4[GR * 65 + 64 * 16];   // 49,664 B; gemm tiles / rows-phase alias
    float4* xs4 = smem4;                          // 32 rows x 64 float4, stride 65 (bank-pad)
    float4* ws4 = smem4 + GR * 65;                // 64 k x 16 float4 (this block's 64 cols)
    int t = threadIdx.x;

    // ---- P1a: GEMM Wh = X @ Ws (32x64 tile) + fused s1/s2 partials -----------------
    {
        int rb = blockIdx.x >> 1, cb = blockIdx.x & 1;
        int row0 = rb * GR;
        const float4* Xg = (const float4*)(X + (size_t)row0 * FDIM);
        for (int i = t; i < GR * 64; i += 256) {
            int r = i >> 6, j = i & 63;
            xs4[r * 65 + j] = Xg[i];
        }
        int rg = t >> 4, cg = t & 15;
        float4 acc0 = make_float4(0.f, 0.f, 0.f, 0.f);
        float4 acc1 = make_float4(0.f, 0.f, 0.f, 0.f);

        for (int c = 0; c < 4; c++) {
            __syncthreads();          // prev chunk consumed (covers xs4 at c=0)
            const float* Wsrc = Ws + (size_t)(c * 64) * DDIM + cb * 64;
            for (int i = t; i < 1024; i += 256) {
                int kk = i >> 4, cc = i & 15;
                ws4[i] = ((const float4*)(Wsrc + (size_t)kk * DDIM))[cc];
            }
            __syncthreads();          // chunk staged
#pragma unroll 4
            for (int kk = 0; kk < 64; kk += 4) {
                float4 w0 = ws4[(kk + 0) * 16 + cg];
                float4 w1 = ws4[(kk + 1) * 16 + cg];
                float4 w2 = ws4[(kk + 2) * 16 + cg];
                float4 w3 = ws4[(kk + 3) * 16 + cg];
                float4 x0 = xs4[(rg * 2 + 0) * 65 + c * 16 + (kk >> 2)];
                float4 x1 = xs4[(rg * 2 + 1) * 65 + c * 16 + (kk >> 2)];
                acc0.x = fmaf(x0.x, w0.x, acc0.x); acc0.x = fmaf(x0.y, w1.x, acc0.x);
                acc0.x = fmaf(x0.z, w2.x, acc0.x); acc0.x = fmaf(x0.w, w3.x, acc0.x);
                acc0.y = fmaf(x0.x, w0.y, acc0.y); acc0.y = fmaf(x0.y, w1.y, acc0.y);
                acc0.y = fmaf(x0.z, w2.y, acc0.y); acc0.y = fmaf(x0.w, w3.y, acc0.y);
                acc0.z = fmaf(x0.x, w0.z, acc0.z); acc0.z = fmaf(x0.y, w1.z, acc0.z);
                acc0.z = fmaf(x0.z, w2.z, acc0.z); acc0.z = fmaf(x0.w, w3.z, acc0.z);
                acc0.w = fmaf(x0.x, w0.w, acc0.w); acc0.w = fmaf(x0.y, w1.w, acc0.w);
                acc0.w = fmaf(x0.z, w2.w, acc0.w); acc0.w = fmaf(x0.w, w3.w, acc0.w);
                acc1.x = fmaf(x1.x, w0.x, acc1.x); acc1.x = fmaf(x1.y, w1.x, acc1.x);
                acc1.x = fmaf(x1.z, w2.x, acc1.x); acc1.x = fmaf(x1.w, w3.x, acc1.x);
                acc1.y = fmaf(x1.x, w0.y, acc1.y); acc1.y = fmaf(x1.y, w1.y, acc1.y);
                acc1.y = fmaf(x1.z, w2.y, acc1.y); acc1.y = fmaf(x1.w, w3.y, acc1.y);
                acc1.z = fmaf(x1.x, w0.z, acc1.z); acc1.z = fmaf(x1.y, w1.z, acc1.z);
                acc1.z = fmaf(x1.z, w2.z, acc1.z); acc1.z = fmaf(x1.w, w3.z, acc1.z);
                acc1.w = fmaf(x1.x, w0.w, acc1.w); acc1.w = fmaf(x1.y, w1.w, acc1.w);
                acc1.w = fmaf(x1.z, w2.w, acc1.w); acc1.w = fmaf(x1.w, w3.w, acc1.w);
            }
        }

        ((float4*)(Wh + (size_t)(row0 + rg * 2 + 0) * DDIM))[cb * 16 + cg] = acc0;
        ((float4*)(Wh + (size_t)(row0 + rg * 2 + 1) * DDIM))[cb * 16 + cg] = acc1;

        float4 a1 = ((const float4*)a)[cb * 16 + cg];
        float4 a2 = ((const float4*)a)[32 + cb * 16 + cg];
        float p10 = acc0.x * a1.x + acc0.y * a1.y + acc0.z * a1.z + acc0.w * a1.w;
        float p20 = acc0.x * a2.x + acc0.y * a2.y + acc0.z * a2.z + acc0.w * a2.w;
        float p11 = acc1.x * a1.x + acc1.y * a1.y + acc1.z * a1.z + acc1.w * a1.w;
        float p21 = acc1.x * a2.x + acc1.y * a2.y + acc1.z * a2.z + acc1.w * a2.w;
        for (int o = 8; o; o >>= 1) {
            p10 += __shfl_xor(p10, o, 16);
            p20 += __shfl_xor(p20, o, 16);
            p11 += __shfl_xor(p11, o, 16);
            p21 += __shfl_xor(p21, o, 16);
        }
        if (cg == 0) {
            // two commutative float addends per address (cb=0,1) -> deterministic sum
            atomicAdd(&s1[row0 + rg * 2 + 0], p10);
            atomicAdd(&s2[row0 + rg * 2 + 0], p20);
            atomicAdd(&s1[row0 + rg * 2 + 1], p11);
            atomicAdd(&s2[row0 + rg * 2 + 1], p21);
        }
    }

    // ---- P1b: ELL build (independent of GEMM; cnt zeroed by zero_k) ---------------
    for (int e = blockIdx.x * 256 + t; e < E; e += GRID * 256) {
        int r = edge[e];
        int c = edge[E + e];
        unsigned slot = atomicAdd(&cnt[r], 1u);
        if (slot < ELLW) ell[(size_t)r * ELLW + slot] = (unsigned)c;
    }

    grid_barrier(gctr);               // Wh/s1/s2/cnt/ell visible device-wide

    // ---- P2: rows — wave-per-row, 4 rows per wave, no block barriers --------------
    {
        unsigned* bmw = (unsigned*)smem4;                 // [4][256] dedup bitmaps
        float*    plv = (float*)(bmw + 4 * 256);          // [4][128]
        unsigned* jlv = (unsigned*)(plv + 4 * 128);       // [4][128]
        int w = t >> 6, lane = t & 63;
        const float2* Wh2 = (const float2*)Wh;

        for (int it = 0; it < 4; ++it) {
            ((uint4*)(bmw + w * 256))[lane] = make_uint4(0u, 0u, 0u, 0u);
            int i = blockIdx.x * 16 + w * 4 + it;
            unsigned deg = cnt[i];
            if (deg > ELLW) deg = ELLW;

            if (deg == 0u) {
                // all-masked row -> uniform softmax -> elu(mean(Wh)); never taken here
                float sx = 0.f, sy = 0.f;
                for (int rr = 0; rr < N_NODES; rr++) {
                    float2 v = Wh2[(size_t)rr * 64 + lane];
                    sx += v.x; sy += v.y;
                }
                sx *= (1.0f / N_NODES); sy *= (1.0f / N_NODES);
                sx = sx > 0.f ? sx : __expf(sx) - 1.f;
                sy = sy > 0.f ? sy : __expf(sy) - 1.f;
                ((float2*)out)[(size_t)i * 64 + lane] = make_float2(sx, sy);
                continue;
            }

            const unsigned* erow = ell + (size_t)i * ELLW;
            unsigned j0 = 0u, j1 = 0u;
            bool v0 = false, v1 = false;
            if (lane < (int)deg) j0 = erow[lane];
            if (lane + 64 < (int)deg) j1 = erow[lane + 64];
            if (lane < (int)deg) {
                unsigned m = 1u << (j0 & 31);
                v0 = !(atomicOr(&bmw[w * 256 + (j0 >> 5)], m) & m);
            }
            if (lane + 64 < (int)deg) {
                unsigned m = 1u << (j1 & 31);
                v1 = !(atomicOr(&bmw[w * 256 + (j1 >> 5)], m) & m);
            }

            float s1i = s1[i];
            float e0 = -3e38f, e1 = -3e38f;
            if (v0) { float e = s1i + s2[j0]; e0 = e > 0.f ? e : SLOPE * e; }
            if (v1) { float e = s1i + s2[j1]; e1 = e > 0.f ? e : SLOPE * e; }

            float mx = fmaxf(e0, e1);
            for (int o = 32; o; o >>= 1) mx = fmaxf(mx, __shfl_xor(mx, o, 64));

            float p0 = v0 ? __expf(e0 - mx) : 0.f;
            float p1 = v1 ? __expf(e1 - mx) : 0.f;
            float s = p0 + p1;
            for (int o = 32; o; o >>= 1) s += __shfl_xor(s, o, 64);
            float inv = 1.0f / s;

            plv[w * ELLW + lane] = p0;      jlv[w * ELLW + lane] = j0;
            plv[w * ELLW + lane + 64] = p1; jlv[w * ELLW + lane + 64] = j1;

            float ax = 0.f, ay = 0.f;
#pragma unroll 4
            for (unsigned n = 0; n < deg; ++n) {
                float p = plv[w * ELLW + n];     // LDS broadcast
                unsigned j = jlv[w * ELLW + n];
                float2 v = Wh2[(size_t)j * 64 + lane];
                ax = fmaf(p, v.x, ax); ay = fmaf(p, v.y, ay);
            }
            ax *= inv; ay *= inv;
            ax = ax > 0.f ? ax : __expf(ax) - 1.f;
            ay = ay > 0.f ? ay : __expf(ay) - 1.f;
            ((float2*)out)[(size_t)i * 64 + lane] = make_float2(ax, ay);
        }
    }
}

extern "C" void kernel_launch(void* const* d_in, const int* in_sizes, int n_in,
                              void* d_out, int out_size, void* d_ws, size_t ws_size,
                              hipStream_t stream) {
    const int*   edge = (const int*)d_in[0];    // [2, E] int32
    const float* X    = (const float*)d_in[1];  // [N, F]
    const float* Ws   = (const float*)d_in[2];  // [F, D]
    const float* a    = (const float*)d_in[3];  // [2D, 1]
    float*       out  = (float*)d_out;          // [N, D]
    int E = in_sizes[0] / 2;

    char* ws = (char*)d_ws;
    unsigned* cnt  = (unsigned*)ws;                                        // 32 KB
    unsigned* gctr = cnt + N_NODES;                                        // 4 B
    unsigned* ell  = (unsigned*)(ws + 64 * 1024);                          // 4 MB
    float*    s1   = (float*)(ws + 64 * 1024 + (size_t)N_NODES * ELLW * 4);// 32 KB
    float*    s2   = s1 + N_NODES;                                         // 32 KB
    float*    Wh   = s2 + N_NODES;                                         // 4 MB

    zero_k<<<N_NODES / 256, 256, 0, stream>>>(cnt, s1, s2, gctr);
    glcn_fused<<<GRID, 256, 0, stream>>>(edge, E, X, Ws, a, Wh, s1, s2,
                                         cnt, ell, out, gctr);
}

// Round 10
// 58.175 us; speedup vs baseline: 2.6879x; 1.9957x over previous
//
#include <hip/hip_runtime.h>
#include <math.h>

#define N_NODES 8192
#define FDIM 256
#define DDIM 128
#define SLOPE 0.2f
#define ELLW 128   // max kept slots/row (incl. dups); true max ~56, validated R5-R9

// ---------------- ELL build: cnt[r] slots, dedup deferred to row phase --------------
__global__ __launch_bounds__(256) void build_ell(const int* __restrict__ edge, int E,
                                                 unsigned* __restrict__ cnt,
                                                 unsigned* __restrict__ ell) {
    int e = blockIdx.x * blockDim.x + threadIdx.x;
    if (e >= E) return;
    int r = edge[e];       // edge_index[0][e] : softmax row
    int c = edge[E + e];   // edge_index[1][e] : neighbor
    unsigned slot = atomicAdd(&cnt[r], 1u);
    if (slot < ELLW) ell[(size_t)r * ELLW + slot] = (unsigned)c;
}

// ---------------- zero-LDS GEMM: lanes=cols (VGPR w), rows wave-uniform (SGPR x) ----
// R4-R7 gemm variants all sat at ~20-29us because they were LDS-BW-bound (~3B/FMA ->
// ~800MB LDS traffic). This version has NO LDS and NO barriers: w[k][col] loads are
// coalesced VGPR reads (L2-hot, 128KB), x[row][k] is wave-uniform -> s_load into
// SGPRs, FMA = v_fmac(acc, s_x, v_w). Each wave: 8 rows x 64 cols x K=256.
// 512 blocks x 4 waves = 2048 waves = 8/CU. Pure-FMA floor ~3.4us.
__global__ __launch_bounds__(256, 2) void gemm_sgpr(const float* __restrict__ X,
                                                    const float* __restrict__ Ws,
                                                    const float* __restrict__ a,
                                                    float* __restrict__ Wh,
                                                    float* __restrict__ s1p,
                                                    float* __restrict__ s2p,
                                                    unsigned* __restrict__ cnt) {
    int t = threadIdx.x;
    int wv = __builtin_amdgcn_readfirstlane(t >> 6);   // wave id 0..3 (force uniform)
    int lane = t & 63;

    // fused zero of ELL counters (gemm precedes build_ell in stream order)
    if (t < 16) cnt[blockIdx.x * 16 + t] = 0u;

    int row0 = blockIdx.x * 16 + (wv & 1) * 8;         // this wave's 8 rows
    int cb   = wv >> 1;                                // col half: 0 or 1
    int col  = cb * 64 + lane;                         // this lane's output column

    const float* __restrict__ Xr = X + (size_t)row0 * FDIM;   // wave-uniform base
    const float* __restrict__ Wc = Ws + col;                  // per-lane column

    float acc[8] = {0.f, 0.f, 0.f, 0.f, 0.f, 0.f, 0.f, 0.f};

    for (int k = 0; k < FDIM; k += 8) {
        // per-lane w: 8 coalesced dword loads (256B/instr, stride 512B)
        float w0 = Wc[(size_t)(k + 0) * DDIM];
        float w1 = Wc[(size_t)(k + 1) * DDIM];
        float w2 = Wc[(size_t)(k + 2) * DDIM];
        float w3 = Wc[(size_t)(k + 3) * DDIM];
        float w4 = Wc[(size_t)(k + 4) * DDIM];
        float w5 = Wc[(size_t)(k + 5) * DDIM];
        float w6 = Wc[(size_t)(k + 6) * DDIM];
        float w7 = Wc[(size_t)(k + 7) * DDIM];
        // wave-uniform x: 8 rows x 8 k -> s_load_dwordx8 per row (aligned, consecutive)
        float x[8][8];
#pragma unroll
        for (int r = 0; r < 8; r++) {
#pragma unroll
            for (int q = 0; q < 8; q++) x[r][q] = Xr[r * FDIM + k + q];
        }
#pragma unroll
        for (int r = 0; r < 8; r++) {
            acc[r] = fmaf(x[r][0], w0, acc[r]);
            acc[r] = fmaf(x[r][1], w1, acc[r]);
            acc[r] = fmaf(x[r][2], w2, acc[r]);
            acc[r] = fmaf(x[r][3], w3, acc[r]);
            acc[r] = fmaf(x[r][4], w4, acc[r]);
            acc[r] = fmaf(x[r][5], w5, acc[r]);
            acc[r] = fmaf(x[r][6], w6, acc[r]);
            acc[r] = fmaf(x[r][7], w7, acc[r]);
        }
    }

    // store Wh: per row, 64 lanes write 256B contiguous
#pragma unroll
    for (int r = 0; r < 8; r++)
        Wh[(size_t)(row0 + r) * DDIM + col] = acc[r];

    // fused s1/s2 partials for this col-half (deterministic: no atomics,
    // halves summed in fixed order by the rows kernel)
    float a1v = a[col], a2v = a[DDIM + col];
#pragma unroll
    for (int r = 0; r < 8; r++) {
        float p1 = acc[r] * a1v;
        float p2 = acc[r] * a2v;
        for (int o = 32; o; o >>= 1) {
            p1 += __shfl_xor(p1, o, 64);
            p2 += __shfl_xor(p2, o, 64);
        }
        if (lane == 0) {
            s1p[(size_t)cb * N_NODES + row0 + r] = p1;
            s2p[(size_t)cb * N_NODES + row0 + r] = p2;
        }
    }
}

// ---------------- wave-per-row: dedup + softmax + gather + elu (R6 structure) -------
__global__ __launch_bounds__(256) void row_wave_k(const unsigned* __restrict__ cnt,
                                                  const unsigned* __restrict__ ell,
                                                  const float* __restrict__ s1p,
                                                  const float* __restrict__ s2p,
                                                  const float* __restrict__ Wh,
                                                  float* __restrict__ out) {
    __shared__ unsigned bmw[4][256];   // per-wave 8192-bit dedup bitmap (1KB each)
    __shared__ float    pl[4][ELLW];
    __shared__ unsigned jl[4][ELLW];

    int w = threadIdx.x >> 6, lane = threadIdx.x & 63;
    int i = blockIdx.x * 4 + w;
    const float2* Wh2 = (const float2*)Wh;

    ((uint4*)bmw[w])[lane] = make_uint4(0u, 0u, 0u, 0u);
    unsigned deg = cnt[i];
    if (deg > ELLW) deg = ELLW;
    __syncthreads();   // single barrier: bitmap zeroes visible

    if (deg == 0u) {
        // all-masked row -> uniform softmax -> elu(mean(Wh)); never taken on this input
        float sx = 0.f, sy = 0.f;
        for (int rr = 0; rr < N_NODES; rr++) {
            float2 v = Wh2[(size_t)rr * 64 + lane];
            sx += v.x; sy += v.y;
        }
        sx *= (1.0f / N_NODES); sy *= (1.0f / N_NODES);
        sx = sx > 0.f ? sx : __expf(sx) - 1.f;
        sy = sy > 0.f ? sy : __expf(sy) - 1.f;
        ((float2*)out)[(size_t)i * 64 + lane] = make_float2(sx, sy);
        return;
    }

    // dedup via LDS atomicOr (0->1 transition unique regardless of op order)
    const unsigned* erow = ell + (size_t)i * ELLW;
    unsigned j0 = 0u, j1 = 0u;
    bool v0 = false, v1 = false;
    if (lane < (int)deg) j0 = erow[lane];
    if (lane + 64 < (int)deg) j1 = erow[lane + 64];
    if (lane < (int)deg) {
        unsigned m = 1u << (j0 & 31);
        v0 = !(atomicOr(&bmw[w][j0 >> 5], m) & m);
    }
    if (lane + 64 < (int)deg) {
        unsigned m = 1u << (j1 & 31);
        v1 = !(atomicOr(&bmw[w][j1 >> 5], m) & m);
    }

    float s1 = s1p[i] + s1p[N_NODES + i];
    float e0 = -3e38f, e1 = -3e38f;
    if (v0) { float e = s1 + s2p[j0] + s2p[N_NODES + j0]; e0 = e > 0.f ? e : SLOPE * e; }
    if (v1) { float e = s1 + s2p[j1] + s2p[N_NODES + j1]; e1 = e > 0.f ? e : SLOPE * e; }

    float mx = fmaxf(e0, e1);
    for (int o = 32; o; o >>= 1) mx = fmaxf(mx, __shfl_xor(mx, o, 64));

    float p0 = v0 ? __expf(e0 - mx) : 0.f;
    float p1 = v1 ? __expf(e1 - mx) : 0.f;
    float s = p0 + p1;
    for (int o = 32; o; o >>= 1) s += __shfl_xor(s, o, 64);
    float inv = 1.0f / s;

    pl[w][lane] = p0;      jl[w][lane] = j0;
    pl[w][lane + 64] = p1; jl[w][lane + 64] = j1;

    // gather: whole wave reads one 512B Wh row per neighbor (float2 per lane)
    float ax = 0.f, ay = 0.f;
#pragma unroll 4
    for (unsigned n = 0; n < deg; ++n) {
        float p = pl[w][n];            // LDS broadcast
        unsigned j = jl[w][n];
        float2 v = Wh2[(size_t)j * 64 + lane];
        ax = fmaf(p, v.x, ax); ay = fmaf(p, v.y, ay);
    }
    ax *= inv; ay *= inv;
    ax = ax > 0.f ? ax : __expf(ax) - 1.f;
    ay = ay > 0.f ? ay : __expf(ay) - 1.f;
    ((float2*)out)[(size_t)i * 64 + lane] = make_float2(ax, ay);
}

extern "C" void kernel_launch(void* const* d_in, const int* in_sizes, int n_in,
                              void* d_out, int out_size, void* d_ws, size_t ws_size,
                              hipStream_t stream) {
    const int*   edge = (const int*)d_in[0];    // [2, E] int32
    const float* X    = (const float*)d_in[1];  // [N, F]
    const float* Ws   = (const float*)d_in[2];  // [F, D]
    const float* a    = (const float*)d_in[3];  // [2D, 1]
    float*       out  = (float*)d_out;          // [N, D]
    int E = in_sizes[0] / 2;

    char* ws = (char*)d_ws;
    unsigned* cnt = (unsigned*)ws;                                        // 32 KB
    unsigned* ell = (unsigned*)(ws + 32 * 1024);                          // 4 MB
    float*    s1p = (float*)(ws + 32 * 1024 + (size_t)N_NODES * ELLW * 4);// 2 x 32 KB
    float*    s2p = s1p + 2 * N_NODES;                                    // 2 x 32 KB
    float*    Wh  = s2p + 2 * N_NODES;                                    // 4 MB

    // gemm first: it also zeros cnt (stream order => done before build_ell)
    gemm_sgpr<<<N_NODES / 16, 256, 0, stream>>>(X, Ws, a, Wh, s1p, s2p, cnt);
    build_ell<<<(E + 255) / 256, 256, 0, stream>>>(edge, E, cnt, ell);
    row_wave_k<<<N_NODES / 4, 256, 0, stream>>>(cnt, ell, s1p, s2p, Wh, out);
}